// Round 3
// baseline (382.064 us; speedup 1.0000x reference)
//
#include <hip/hip_runtime.h>
#include <hip/hip_bf16.h>
#include <stdint.h>

#define TOKENS 8192
#define IN_F   4096
#define OUT_F  4096
#define GROUP  128

#define BM 128
#define BN 128
#define BK 32

typedef __attribute__((ext_vector_type(8))) short short8;
typedef __attribute__((ext_vector_type(4))) float f32x4;

// ---------------------------------------------------------------------------
// Kernel 1: convert x fp32 -> bf16 (workspace). 8 floats / thread-item.
// ---------------------------------------------------------------------------
__global__ void k_convert_x(const float* __restrict__ x,
                            __hip_bfloat16* __restrict__ xb) {
  const int64_t total = (int64_t)TOKENS * IN_F / 8;
  const int64_t stride = (int64_t)gridDim.x * blockDim.x;
  for (int64_t i = (int64_t)blockIdx.x * blockDim.x + threadIdx.x; i < total;
       i += stride) {
    const float4* p = reinterpret_cast<const float4*>(x) + i * 2;
    float4 a = p[0];
    float4 b = p[1];
    union {
      short8 v;
      __hip_bfloat16 h[8];
    } r;
    r.h[0] = __float2bfloat16(a.x);
    r.h[1] = __float2bfloat16(a.y);
    r.h[2] = __float2bfloat16(a.z);
    r.h[3] = __float2bfloat16(a.w);
    r.h[4] = __float2bfloat16(b.x);
    r.h[5] = __float2bfloat16(b.y);
    r.h[6] = __float2bfloat16(b.z);
    r.h[7] = __float2bfloat16(b.w);
    reinterpret_cast<short8*>(xb)[i] = r.v;
  }
}

// ---------------------------------------------------------------------------
// Kernel 2: dequantize qweight -> W^T bf16 [OUT_F][IN_F] (workspace).
// W[k][n] = s[g][n] * (w - z[g][n]), g = k/GROUP  (no +1 on zeros).
// Tile: 256 n x 64 k, transposed through LDS so global writes are
// 128B-contiguous runs (8 lanes x 16B per W^T row).
// ---------------------------------------------------------------------------
__global__ void k_dequant(const int* __restrict__ qweight,
                          const int* __restrict__ qzeros,
                          const float* __restrict__ scales,
                          __hip_bfloat16* __restrict__ wt) {
  __shared__ __align__(16) __hip_bfloat16 sW[256][72];  // [n][k], +8 pad
  const int nt = blockIdx.x & 15;   // 16 n-tiles
  const int kt = blockIdx.x >> 4;   // 64 k-tiles
  const int n0 = nt * 256;
  const int k0 = kt * 64;           // multiple of 64 -> single group
  const int g = k0 / GROUP;
  const int t = threadIdx.x;
  const int n = n0 + t;

  const float s = scales[(size_t)g * OUT_F + n];
  const unsigned zw =
      ((const unsigned*)qzeros)[(size_t)g * (OUT_F / 8) + (n >> 3)];
  const float z = (float)((zw >> ((n & 7) * 4)) & 15u);
  const float sz = s * z;
  const int kw0 = k0 >> 3;
#pragma unroll
  for (int kw = 0; kw < 8; ++kw) {
    const unsigned w = ((const unsigned*)qweight)[(size_t)(kw0 + kw) * OUT_F + n];
#pragma unroll
    for (int j = 0; j < 8; ++j) {
      const float q = (float)((w >> (4 * j)) & 15u);
      sW[t][kw * 8 + j] = __float2bfloat16(s * q - sz);
    }
  }
  __syncthreads();
#pragma unroll
  for (int pass = 0; pass < 8; ++pass) {
    const int row = pass * 32 + (t >> 3);
    const int kc = t & 7;
    short8 v = *reinterpret_cast<const short8*>(&sW[row][kc * 8]);
    *reinterpret_cast<short8*>(wt + (size_t)(n0 + row) * IN_F + k0 + kc * 8) = v;
  }
}

// ---------------------------------------------------------------------------
// Kernel 3: bf16 MFMA GEMM (m97 structure): 128x128 tile, BK=32, 4 waves,
// global_load_lds width-16 staging, 4x4 16x16x32 fragments per wave,
// fused bias epilogue, fp32 out.
// ---------------------------------------------------------------------------
__device__ inline void gload_lds16(const void* g, void* l) {
  __builtin_amdgcn_global_load_lds(
      (const __attribute__((address_space(1))) void*)g,
      (__attribute__((address_space(3))) void*)l, 16, 0, 0);
}

__global__ __launch_bounds__(256) void k_gemm(
    const __hip_bfloat16* __restrict__ xb,  // [TOKENS][IN_F]
    const __hip_bfloat16* __restrict__ wt,  // [OUT_F][IN_F]
    const float* __restrict__ bias,         // [OUT_F]
    float* __restrict__ out) {              // [TOKENS][OUT_F]
  __shared__ __align__(16) __hip_bfloat16 As[BM][BK];  // 8 KB
  __shared__ __align__(16) __hip_bfloat16 Bs[BN][BK];  // 8 KB

  const int mtiles = TOKENS / BM;  // 64 (fast-varying: reuse B panel in L2)
  const int bm = blockIdx.x % mtiles;
  const int bn = blockIdx.x / mtiles;
  const int m0 = bm * BM;
  const int n0 = bn * BN;
  const int t = threadIdx.x;
  const int lane = t & 63;
  const int wid = t >> 6;
  const int wr = wid >> 1;  // 2x2 wave grid, each wave owns 64x64
  const int wc = wid & 1;

  f32x4 acc[4][4];
#pragma unroll
  for (int i = 0; i < 4; ++i)
#pragma unroll
    for (int j = 0; j < 4; ++j) acc[i][j] = (f32x4){0.f, 0.f, 0.f, 0.f};

  const char* Ag = (const char*)(xb + (size_t)m0 * IN_F);
  const char* Bg = (const char*)(wt + (size_t)n0 * IN_F);

  const int fr = lane & 15;  // frag row (A: m) / frag col (B: n)
  const int h = lane >> 4;   // k-quarter index (8 bf16 each)

  for (int kt = 0; kt < IN_F; kt += BK) {
    __syncthreads();
    // Stage A and B tiles: 8 KB each = 8 wave-instructions each (2/wave).
    // chunk c = t + 256*i; LDS lane slot = c*16B; row = c/4, off = (c%4)*16.
#pragma unroll
    for (int i = 0; i < 2; ++i) {
      const int c = t + 256 * i;
      const int row = c >> 2;
      const int off = (c & 3) * 16;
      const size_t gofs = (size_t)row * (IN_F * 2) + (size_t)kt * 2 + off;
      gload_lds16(Ag + gofs, (char*)As + (wid + 4 * i) * 1024);
      gload_lds16(Bg + gofs, (char*)Bs + (wid + 4 * i) * 1024);
    }
    __syncthreads();  // compiler drains vmcnt(0) before s_barrier

    short8 a[4], b[4];
#pragma unroll
    for (int mf = 0; mf < 4; ++mf)
      a[mf] = *reinterpret_cast<const short8*>(&As[wr * 64 + mf * 16 + fr][h * 8]);
#pragma unroll
    for (int nf = 0; nf < 4; ++nf)
      b[nf] = *reinterpret_cast<const short8*>(&Bs[wc * 64 + nf * 16 + fr][h * 8]);
#pragma unroll
    for (int mf = 0; mf < 4; ++mf)
#pragma unroll
      for (int nf = 0; nf < 4; ++nf)
        acc[mf][nf] = __builtin_amdgcn_mfma_f32_16x16x32_bf16(
            a[mf], b[nf], acc[mf][nf], 0, 0, 0);
  }

  // Epilogue: C/D layout col = lane&15 (n), row = (lane>>4)*4 + reg (m).
  const int h4 = (lane >> 4) * 4;
  float bv[4];
#pragma unroll
  for (int nf = 0; nf < 4; ++nf) bv[nf] = bias[n0 + wc * 64 + nf * 16 + fr];
#pragma unroll
  for (int mf = 0; mf < 4; ++mf) {
    const int m = m0 + wr * 64 + mf * 16 + h4;
#pragma unroll
    for (int nf = 0; nf < 4; ++nf) {
      const int n = n0 + wc * 64 + nf * 16 + fr;
      float* o = out + (size_t)m * OUT_F + n;
#pragma unroll
      for (int r = 0; r < 4; ++r) o[(size_t)r * OUT_F] = acc[mf][nf][r] + bv[nf];
    }
  }
}

// ---------------------------------------------------------------------------
extern "C" void kernel_launch(void* const* d_in, const int* in_sizes, int n_in,
                              void* d_out, int out_size, void* d_ws,
                              size_t ws_size, hipStream_t stream) {
  const float* x = (const float*)d_in[0];
  const int* qweight = (const int*)d_in[1];
  const int* qzeros = (const int*)d_in[2];
  const float* scales = (const float*)d_in[3];
  const float* bias = (const float*)d_in[4];
  // d_in[5] = g_idx, deterministic (k/GROUP) -> folded into kernel.
  float* out = (float*)d_out;

  __hip_bfloat16* xb = (__hip_bfloat16*)d_ws;               // 64 MiB
  __hip_bfloat16* wt = xb + (size_t)TOKENS * IN_F;          // +32 MiB

  k_convert_x<<<2048, 256, 0, stream>>>(x, xb);
  k_dequant<<<1024, 256, 0, stream>>>(qweight, qzeros, scales, wt);
  k_gemm<<<(TOKENS / BM) * (OUT_F / BN), 256, 0, stream>>>(xb, wt, bias, out);
}

// Round 5
// 298.944 us; speedup vs baseline: 1.2780x; 1.2780x over previous
//
#include <hip/hip_runtime.h>
#include <hip/hip_bf16.h>
#include <stdint.h>

#define TOKENS 8192
#define IN_F   4096
#define OUT_F  4096
#define GROUP  128

typedef __attribute__((ext_vector_type(8))) short short8;
typedef __attribute__((ext_vector_type(4))) float f32x4;

// ---------------------------------------------------------------------------
// Kernel 1: convert x fp32 -> bf16 (workspace). 8 floats / thread-item.
// ---------------------------------------------------------------------------
__global__ void k_convert_x(const float* __restrict__ x,
                            __hip_bfloat16* __restrict__ xb) {
  const int64_t total = (int64_t)TOKENS * IN_F / 8;
  const int64_t stride = (int64_t)gridDim.x * blockDim.x;
  for (int64_t i = (int64_t)blockIdx.x * blockDim.x + threadIdx.x; i < total;
       i += stride) {
    const float4* p = reinterpret_cast<const float4*>(x) + i * 2;
    float4 a = p[0];
    float4 b = p[1];
    union {
      short8 v;
      __hip_bfloat16 h[8];
    } r;
    r.h[0] = __float2bfloat16(a.x);
    r.h[1] = __float2bfloat16(a.y);
    r.h[2] = __float2bfloat16(a.z);
    r.h[3] = __float2bfloat16(a.w);
    r.h[4] = __float2bfloat16(b.x);
    r.h[5] = __float2bfloat16(b.y);
    r.h[6] = __float2bfloat16(b.z);
    r.h[7] = __float2bfloat16(b.w);
    reinterpret_cast<short8*>(xb)[i] = r.v;
  }
}

// ---------------------------------------------------------------------------
// Kernel 2: dequantize qweight -> W^T bf16 [OUT_F][IN_F] (workspace).
// ---------------------------------------------------------------------------
__global__ void k_dequant(const int* __restrict__ qweight,
                          const int* __restrict__ qzeros,
                          const float* __restrict__ scales,
                          __hip_bfloat16* __restrict__ wt) {
  __shared__ __align__(16) __hip_bfloat16 sW[256][72];  // [n][k], +8 pad
  const int nt = blockIdx.x & 15;   // 16 n-tiles
  const int kt = blockIdx.x >> 4;   // 64 k-tiles
  const int n0 = nt * 256;
  const int k0 = kt * 64;           // multiple of 64 -> single group
  const int g = k0 / GROUP;
  const int t = threadIdx.x;
  const int n = n0 + t;

  const float s = scales[(size_t)g * OUT_F + n];
  const unsigned zw =
      ((const unsigned*)qzeros)[(size_t)g * (OUT_F / 8) + (n >> 3)];
  const float z = (float)((zw >> ((n & 7) * 4)) & 15u);
  const float sz = s * z;
  const int kw0 = k0 >> 3;
#pragma unroll
  for (int kw = 0; kw < 8; ++kw) {
    const unsigned w = ((const unsigned*)qweight)[(size_t)(kw0 + kw) * OUT_F + n];
#pragma unroll
    for (int j = 0; j < 8; ++j) {
      const float q = (float)((w >> (4 * j)) & 15u);
      sW[t][kw * 8 + j] = __float2bfloat16(s * q - sz);
    }
  }
  __syncthreads();
#pragma unroll
  for (int pass = 0; pass < 8; ++pass) {
    const int row = pass * 32 + (t >> 3);
    const int kc = t & 7;
    short8 v = *reinterpret_cast<const short8*>(&sW[row][kc * 8]);
    *reinterpret_cast<short8*>(wt + (size_t)(n0 + row) * IN_F + k0 + kc * 8) = v;
  }
}

// ---------------------------------------------------------------------------
// Kernel 3: 256x256 8-phase bf16 MFMA GEMM (T1+T2+T3+T4+T5).
// 512 threads = 8 waves (2M x 4N), BK=64, 2x64KiB LDS dbuf.
// A staged in halves rows[0..127]/[128..255]; READ_A(mh) reads rows
// mh*128 + wr*64 + mfl*16 + fr  ->  phase quadrant mh aligns EXACTLY with
// the staged half (fixes round-3 WAR bug where phase-2 staging overwrote
// rows 64..127 still needed by phase 3).
// LDS chunk swizzle: slot(row,cc) holds global chunk cc^(row&7); applied as
// inverse-swizzled global SOURCE (linear global_load_lds dest) + swizzled
// ds_read address. vmcnt(6) only at phases 4/8 (3 half-tiles in flight).
// ---------------------------------------------------------------------------
__device__ inline void gload_lds16(const void* g, void* l) {
  __builtin_amdgcn_global_load_lds(
      (const __attribute__((address_space(1))) void*)g,
      (__attribute__((address_space(3))) void*)l, 16, 0, 0);
}

// buf: 0/1, matsel: 0=A 1=B, half: 0/1 (rows half*128..+127), tile: k-tile
#define STAGE(buf, matsel, half, tile)                                        \
  do {                                                                        \
    const char* gb_ = (matsel) ? Bg : Ag;                                     \
    const int lm_ = (buf)*65536 + (matsel)*32768 + (half)*16384;              \
    _Pragma("unroll") for (int r_ = 0; r_ < 2; ++r_) {                        \
      gload_lds16(gb_ + (size_t)(half)*1048576 + goff[r_] +                   \
                      (size_t)(tile)*128,                                     \
                  smem + lm_ + ldsoff[r_]);                                   \
    }                                                                         \
  } while (0)

// A-frag read: quadrant mh -> a[0..3][0..1]; rows mh*128 + wr*64 (+0..63)
#define READ_A(buf, mh)                                                       \
  do {                                                                        \
    _Pragma("unroll") for (int mfl_ = 0; mfl_ < 4; ++mfl_) {                  \
      const int row_ = (mh)*128 + wr * 64 + mfl_ * 16 + fr;                   \
      const char* p_ = smem + (buf)*65536 + row_ * 128;                       \
      a[mfl_][0] = *reinterpret_cast<const short8*>(p_ + csw0);               \
      a[mfl_][1] = *reinterpret_cast<const short8*>(p_ + csw1);               \
    }                                                                         \
  } while (0)

// B-frag read: n-half nh -> b[nh*2..nh*2+1][0..1]
#define READ_B(buf, nh)                                                       \
  do {                                                                        \
    _Pragma("unroll") for (int nfl_ = 0; nfl_ < 2; ++nfl_) {                  \
      const int row_ = wc * 64 + ((nh)*2 + nfl_) * 16 + fr;                   \
      const char* p_ = smem + (buf)*65536 + 32768 + row_ * 128;               \
      b[(nh)*2 + nfl_][0] = *reinterpret_cast<const short8*>(p_ + csw0);      \
      b[(nh)*2 + nfl_][1] = *reinterpret_cast<const short8*>(p_ + csw1);      \
    }                                                                         \
  } while (0)

#define MMA_Q(mh, nh)                                                         \
  do {                                                                        \
    _Pragma("unroll") for (int mfl_ = 0; mfl_ < 4; ++mfl_)                    \
        _Pragma("unroll") for (int nfl_ = 0; nfl_ < 2; ++nfl_) {              \
      const int mf_ = (mh)*4 + mfl_, nf_ = (nh)*2 + nfl_;                     \
      acc[mf_][nf_] = __builtin_amdgcn_mfma_f32_16x16x32_bf16(                \
          a[mfl_][0], b[nf_][0], acc[mf_][nf_], 0, 0, 0);                     \
      acc[mf_][nf_] = __builtin_amdgcn_mfma_f32_16x16x32_bf16(                \
          a[mfl_][1], b[nf_][1], acc[mf_][nf_], 0, 0, 0);                     \
    }                                                                         \
  } while (0)

#define PH_PRE()                                                              \
  __builtin_amdgcn_sched_barrier(0);                                          \
  __builtin_amdgcn_s_barrier();                                               \
  asm volatile("s_waitcnt lgkmcnt(0)" ::: "memory");                          \
  __builtin_amdgcn_sched_barrier(0);                                          \
  __builtin_amdgcn_s_setprio(1)

#define PH_POST()                                                             \
  __builtin_amdgcn_s_setprio(0);                                              \
  __builtin_amdgcn_sched_barrier(0);                                          \
  __builtin_amdgcn_s_barrier()

__global__ __launch_bounds__(512, 2) void k_gemm256(
    const __hip_bfloat16* __restrict__ xb,  // [TOKENS][IN_F]
    const __hip_bfloat16* __restrict__ wt,  // [OUT_F][IN_F]
    const float* __restrict__ bias,         // [OUT_F]
    float* __restrict__ out) {              // [TOKENS][OUT_F]
  extern __shared__ __align__(16) char smem[];  // 131072 B

  // bijective XCD swizzle: 512 wgs, 512 % 8 == 0
  const int wg = (blockIdx.x & 7) * 64 + (blockIdx.x >> 3);
  const int bm = wg & 31;   // 32 m-tiles (fast -> XCD shares B-panels)
  const int bn = wg >> 5;   // 16 n-tiles
  const int m0 = bm * 256;
  const int n0 = bn * 256;

  const int t = threadIdx.x;
  const int lane = t & 63;
  const int wid = t >> 6;       // 8 waves
  const int wr = wid >> 2;      // 2 (M): 64-row sub-block within quadrant
  const int wc = wid & 3;       // 4 (N)
  const int fr = lane & 15;
  const int hq = lane >> 4;     // 0..3, k-quarter

  // swizzled ds_read chunk byte offsets (row&7 == fr&7 for all frag rows)
  const int csw0 = ((hq ^ (fr & 7))) * 16;        // kk=0
  const int csw1 = ((hq ^ (fr & 7)) ^ 4) * 16;    // kk=1

  // staging per-thread constants: round r covers chunk c = r*512 + t
  int goff[2], ldsoff[2];
#pragma unroll
  for (int r = 0; r < 2; ++r) {
    const int srow = r * 64 + wid * 8 + (lane >> 3);        // 0..127
    const int schunk = (lane & 7) ^ (srow & 7);             // inverse swizzle
    goff[r] = srow * (IN_F * 2) + schunk * 16;
    ldsoff[r] = (r * 512 + wid * 64) * 16;                  // wave-uniform
  }

  const char* Ag = (const char*)(xb + (size_t)m0 * IN_F);
  const char* Bg = (const char*)(wt + (size_t)n0 * IN_F);

  f32x4 acc[8][4];
#pragma unroll
  for (int i = 0; i < 8; ++i)
#pragma unroll
    for (int j = 0; j < 4; ++j) acc[i][j] = (f32x4){0.f, 0.f, 0.f, 0.f};

  short8 a[4][2];  // current quadrant's m frags
  short8 b[4][2];  // all n frags

  // ---- prologue: tile0 (buf0, 4 half-tiles) + tile1 (buf1, 3 half-tiles)
  STAGE(0, 0, 0, 0);
  STAGE(0, 0, 1, 0);
  STAGE(0, 1, 0, 0);
  STAGE(0, 1, 1, 0);
  STAGE(1, 0, 0, 1);
  STAGE(1, 1, 0, 1);
  STAGE(1, 1, 1, 1);
  asm volatile("s_waitcnt vmcnt(6)" ::: "memory");
  __builtin_amdgcn_s_barrier();

  // ---- main loop: 2 K-tiles (T in buf0, T+1 in buf1) per iteration
  for (int it = 0; it < IN_F / 128; ++it) {
    const int T = 2 * it;
    const int P0 = (T + 2) & 63;
    const int P1 = (T + 3) & 63;

    // phase 1: quadrant (mh=0,nh=0) of tile T; reads A rows 0..127 (half 0)
    READ_A(0, 0);
    READ_B(0, 0);
    STAGE(1, 0, 1, T + 1);  // A-h1 of T+1 -> buf1 (last read: prev phase 7)
    PH_PRE();
    MMA_Q(0, 0);
    PH_POST();

    // phase 2: (0,1) — A half 0 reads done after this phase's bar? no: A
    // half 0 was fully read in phase 1+2 quadrant mh=0 only -> last read ph1?
    // mh=0 used in phases 1 and 2 (a[] regs persist; no new A read here).
    READ_B(0, 1);
    STAGE(0, 0, 0, P0);  // A-h0 of T+2 (A-h0 last ds_read: phase 1)
    PH_PRE();
    MMA_Q(0, 1);
    PH_POST();

    // phase 3: (1,0) — reads A rows 128..255 (half 1)
    READ_A(0, 1);
    STAGE(0, 1, 0, P0);  // B-h0 of T+2 (buf0 B last read: phase 2)
    PH_PRE();
    MMA_Q(1, 0);
    PH_POST();

    // phase 4: (1,1) — counted vmcnt: prev-iter buf1 stages + U1 landed
    STAGE(0, 1, 1, P0);  // B-h1 of T+2
    asm volatile("s_waitcnt vmcnt(6)" ::: "memory");
    PH_PRE();
    MMA_Q(1, 1);
    PH_POST();

    // phase 5: (0,0) of tile T+1 (buf1)
    READ_A(1, 0);
    READ_B(1, 0);
    STAGE(0, 0, 1, P0);  // A-h1 of T+2 (buf0 A-h1 last read: phase 3)
    PH_PRE();
    MMA_Q(0, 0);
    PH_POST();

    // phase 6: (0,1)
    READ_B(1, 1);
    STAGE(1, 0, 0, P1);  // A-h0 of T+3 (buf1 A-h0 last read: phase 5)
    PH_PRE();
    MMA_Q(0, 1);
    PH_POST();

    // phase 7: (1,0)
    READ_A(1, 1);
    STAGE(1, 1, 0, P1);  // B-h0 of T+3 (buf1 B last read: phase 6)
    PH_PRE();
    MMA_Q(1, 0);
    PH_POST();

    // phase 8: (1,1) — counted vmcnt: T+2 (B0,A0,B1,A1) landed for next iter
    STAGE(1, 1, 1, P1);  // B-h1 of T+3
    asm volatile("s_waitcnt vmcnt(6)" ::: "memory");
    PH_PRE();
    MMA_Q(1, 1);
    PH_POST();
  }

  // ---- epilogue: C/D layout col=lane&15 (n), row=(lane>>4)*4+reg (m)
  // acc[mf][nf]: m = m0 + (mf>>2)*128 + wr*64 + (mf&3)*16 + h4 + r
  const int h4 = hq * 4;
  float bv[4];
#pragma unroll
  for (int nf = 0; nf < 4; ++nf) bv[nf] = bias[n0 + wc * 64 + nf * 16 + fr];
#pragma unroll
  for (int mf = 0; mf < 8; ++mf) {
    const int m = m0 + (mf >> 2) * 128 + wr * 64 + (mf & 3) * 16 + h4;
#pragma unroll
    for (int nf = 0; nf < 4; ++nf) {
      const int n = n0 + wc * 64 + nf * 16 + fr;
      float* o = out + (size_t)m * OUT_F + n;
#pragma unroll
      for (int r = 0; r < 4; ++r) o[(size_t)r * OUT_F] = acc[mf][nf][r] + bv[nf];
    }
  }
}

// ---------------------------------------------------------------------------
extern "C" void kernel_launch(void* const* d_in, const int* in_sizes, int n_in,
                              void* d_out, int out_size, void* d_ws,
                              size_t ws_size, hipStream_t stream) {
  const float* x = (const float*)d_in[0];
  const int* qweight = (const int*)d_in[1];
  const int* qzeros = (const int*)d_in[2];
  const float* scales = (const float*)d_in[3];
  const float* bias = (const float*)d_in[4];
  float* out = (float*)d_out;

  __hip_bfloat16* xb = (__hip_bfloat16*)d_ws;       // 64 MiB
  __hip_bfloat16* wt = xb + (size_t)TOKENS * IN_F;  // +32 MiB

  // opt-in to 128 KiB dynamic LDS (idempotent; capture-safe, ran in round 3)
  (void)hipFuncSetAttribute(reinterpret_cast<const void*>(&k_gemm256),
                            hipFuncAttributeMaxDynamicSharedMemorySize, 131072);

  k_convert_x<<<2048, 256, 0, stream>>>(x, xb);
  k_dequant<<<1024, 256, 0, stream>>>(qweight, qzeros, scales, wt);
  k_gemm256<<<(TOKENS / 256) * (OUT_F / 256), 512, 131072, stream>>>(xb, wt,
                                                                     bias, out);
}

// Round 6
// 276.278 us; speedup vs baseline: 1.3829x; 1.0820x over previous
//
#include <hip/hip_runtime.h>
#include <hip/hip_bf16.h>
#include <stdint.h>

#define TOKENS 8192
#define IN_F   4096
#define OUT_F  4096
#define GROUP  128

typedef __attribute__((ext_vector_type(8))) short short8;
typedef __attribute__((ext_vector_type(4))) float f32x4;

// ---------------------------------------------------------------------------
// Kernel 1: convert x fp32 -> bf16 (workspace). 8 floats / thread-item.
// ---------------------------------------------------------------------------
__global__ void k_convert_x(const float* __restrict__ x,
                            __hip_bfloat16* __restrict__ xb) {
  const int64_t total = (int64_t)TOKENS * IN_F / 8;
  const int64_t stride = (int64_t)gridDim.x * blockDim.x;
  for (int64_t i = (int64_t)blockIdx.x * blockDim.x + threadIdx.x; i < total;
       i += stride) {
    const float4* p = reinterpret_cast<const float4*>(x) + i * 2;
    float4 a = p[0];
    float4 b = p[1];
    union {
      short8 v;
      __hip_bfloat16 h[8];
    } r;
    r.h[0] = __float2bfloat16(a.x);
    r.h[1] = __float2bfloat16(a.y);
    r.h[2] = __float2bfloat16(a.z);
    r.h[3] = __float2bfloat16(a.w);
    r.h[4] = __float2bfloat16(b.x);
    r.h[5] = __float2bfloat16(b.y);
    r.h[6] = __float2bfloat16(b.z);
    r.h[7] = __float2bfloat16(b.w);
    reinterpret_cast<short8*>(xb)[i] = r.v;
  }
}

// ---------------------------------------------------------------------------
// Kernel 2: dequantize qweight -> W^T bf16 [OUT_F][IN_F] (workspace).
// ---------------------------------------------------------------------------
__global__ void k_dequant(const int* __restrict__ qweight,
                          const int* __restrict__ qzeros,
                          const float* __restrict__ scales,
                          __hip_bfloat16* __restrict__ wt) {
  __shared__ __align__(16) __hip_bfloat16 sW[256][72];  // [n][k], +8 pad
  const int nt = blockIdx.x & 15;   // 16 n-tiles
  const int kt = blockIdx.x >> 4;   // 64 k-tiles
  const int n0 = nt * 256;
  const int k0 = kt * 64;           // multiple of 64 -> single group
  const int g = k0 / GROUP;
  const int t = threadIdx.x;
  const int n = n0 + t;

  const float s = scales[(size_t)g * OUT_F + n];
  const unsigned zw =
      ((const unsigned*)qzeros)[(size_t)g * (OUT_F / 8) + (n >> 3)];
  const float z = (float)((zw >> ((n & 7) * 4)) & 15u);
  const float sz = s * z;
  const int kw0 = k0 >> 3;
#pragma unroll
  for (int kw = 0; kw < 8; ++kw) {
    const unsigned w = ((const unsigned*)qweight)[(size_t)(kw0 + kw) * OUT_F + n];
#pragma unroll
    for (int j = 0; j < 8; ++j) {
      const float q = (float)((w >> (4 * j)) & 15u);
      sW[t][kw * 8 + j] = __float2bfloat16(s * q - sz);
    }
  }
  __syncthreads();
#pragma unroll
  for (int pass = 0; pass < 8; ++pass) {
    const int row = pass * 32 + (t >> 3);
    const int kc = t & 7;
    short8 v = *reinterpret_cast<const short8*>(&sW[row][kc * 8]);
    *reinterpret_cast<short8*>(wt + (size_t)(n0 + row) * IN_F + k0 + kc * 8) = v;
  }
}

// ---------------------------------------------------------------------------
// Kernel 3: 256x256 8-phase bf16 MFMA GEMM (T1+T2+T3+T4+T5 + read-ahead).
// 512 threads = 8 waves (2M x 4N), BK=64, 2x64KiB LDS dbuf.
// Round-5 change A: one-phase READ-AHEAD — each phase's ds_reads issue
// inside the PREVIOUS phase's MFMA window (fragment ping-pong aX/aY),
// so the PH_PRE lgkmcnt(0) finds them already complete (they had a full
// MFMA window ~600cy >> ds latency ~150cy to land). Read/stage/WAR
// dependency matrix re-verified phase by phase.
// Round-5 change B: 2D XCD chunking — each XCD works a 2bm x 16bn chunk
// per round (A panels 4MB L2-resident, B via L3), instead of all-32-bm
// (which re-streamed A 8x = 553MB FETCH).
// ---------------------------------------------------------------------------
__device__ inline void gload_lds16(const void* g, void* l) {
  __builtin_amdgcn_global_load_lds(
      (const __attribute__((address_space(1))) void*)g,
      (__attribute__((address_space(3))) void*)l, 16, 0, 0);
}

// buf: 0/1, matsel: 0=A 1=B, half: 0/1 (rows half*128..+127), tile: k-tile
#define STAGE(buf, matsel, half, tile)                                        \
  do {                                                                        \
    const char* gb_ = (matsel) ? Bg : Ag;                                     \
    const int lm_ = (buf)*65536 + (matsel)*32768 + (half)*16384;              \
    _Pragma("unroll") for (int r_ = 0; r_ < 2; ++r_) {                        \
      gload_lds16(gb_ + (size_t)(half)*1048576 + goff[r_] +                   \
                      (size_t)(tile)*128,                                     \
                  smem + lm_ + ldsoff[r_]);                                   \
    }                                                                         \
  } while (0)

// A-frag read into named dst set: rows mh*128 + wr*64 + mfl*16 + fr
#define READ_A(buf, mh, dst)                                                  \
  do {                                                                        \
    _Pragma("unroll") for (int mfl_ = 0; mfl_ < 4; ++mfl_) {                  \
      const int row_ = (mh)*128 + wr * 64 + mfl_ * 16 + fr;                   \
      const char* p_ = smem + (buf)*65536 + row_ * 128;                       \
      dst[mfl_][0] = *reinterpret_cast<const short8*>(p_ + csw0);             \
      dst[mfl_][1] = *reinterpret_cast<const short8*>(p_ + csw1);             \
    }                                                                         \
  } while (0)

// B-frag read: n-half nh -> b[nh*2..nh*2+1][0..1]
#define READ_B(buf, nh)                                                       \
  do {                                                                        \
    _Pragma("unroll") for (int nfl_ = 0; nfl_ < 2; ++nfl_) {                  \
      const int row_ = wc * 64 + ((nh)*2 + nfl_) * 16 + fr;                   \
      const char* p_ = smem + (buf)*65536 + 32768 + row_ * 128;               \
      b[(nh)*2 + nfl_][0] = *reinterpret_cast<const short8*>(p_ + csw0);      \
      b[(nh)*2 + nfl_][1] = *reinterpret_cast<const short8*>(p_ + csw1);      \
    }                                                                         \
  } while (0)

#define MMA_Q(aset, mh, nh)                                                   \
  do {                                                                        \
    _Pragma("unroll") for (int mfl_ = 0; mfl_ < 4; ++mfl_)                    \
        _Pragma("unroll") for (int nfl_ = 0; nfl_ < 2; ++nfl_) {              \
      const int mf_ = (mh)*4 + mfl_, nf_ = (nh)*2 + nfl_;                     \
      acc[mf_][nf_] = __builtin_amdgcn_mfma_f32_16x16x32_bf16(                \
          aset[mfl_][0], b[nf_][0], acc[mf_][nf_], 0, 0, 0);                  \
      acc[mf_][nf_] = __builtin_amdgcn_mfma_f32_16x16x32_bf16(                \
          aset[mfl_][1], b[nf_][1], acc[mf_][nf_], 0, 0, 0);                  \
    }                                                                         \
  } while (0)

#define PH_PRE()                                                              \
  __builtin_amdgcn_sched_barrier(0);                                          \
  __builtin_amdgcn_s_barrier();                                               \
  asm volatile("s_waitcnt lgkmcnt(0)" ::: "memory");                          \
  __builtin_amdgcn_sched_barrier(0);                                          \
  __builtin_amdgcn_s_setprio(1)

#define PH_POST()                                                             \
  __builtin_amdgcn_s_setprio(0);                                              \
  __builtin_amdgcn_sched_barrier(0);                                          \
  __builtin_amdgcn_s_barrier()

__global__ __launch_bounds__(512, 2) void k_gemm256(
    const __hip_bfloat16* __restrict__ xb,  // [TOKENS][IN_F]
    const __hip_bfloat16* __restrict__ wt,  // [OUT_F][IN_F]
    const float* __restrict__ bias,         // [OUT_F]
    float* __restrict__ out) {              // [TOKENS][OUT_F]
  extern __shared__ __align__(16) char smem[];  // 131072 B

  // 2D XCD chunking (bijective): XCD x gets 2bm x 16bn per round.
  {
  }
  const int bidx = blockIdx.x;
  const int xcd = bidx & 7;
  const int slot = bidx >> 3;          // 0..63
  const int rnd = slot >> 5;           // 0/1
  const int j = slot & 31;
  const int bm = rnd * 16 + xcd * 2 + (j >> 4);  // 0..31
  const int bn = j & 15;                          // 0..15
  const int m0 = bm * 256;
  const int n0 = bn * 256;

  const int t = threadIdx.x;
  const int lane = t & 63;
  const int wid = t >> 6;       // 8 waves
  const int wr = wid >> 2;      // 2 (M): 64-row sub-block within quadrant
  const int wc = wid & 3;       // 4 (N)
  const int fr = lane & 15;
  const int hq = lane >> 4;     // 0..3, k-quarter

  // swizzled ds_read chunk byte offsets (row&7 == fr&7 for all frag rows)
  const int csw0 = ((hq ^ (fr & 7))) * 16;        // kk=0
  const int csw1 = ((hq ^ (fr & 7)) ^ 4) * 16;    // kk=1

  // staging per-thread constants: round r covers chunk c = r*512 + t
  int goff[2], ldsoff[2];
#pragma unroll
  for (int r = 0; r < 2; ++r) {
    const int srow = r * 64 + wid * 8 + (lane >> 3);        // 0..127
    const int schunk = (lane & 7) ^ (srow & 7);             // inverse swizzle
    goff[r] = srow * (IN_F * 2) + schunk * 16;
    ldsoff[r] = (r * 512 + wid * 64) * 16;                  // wave-uniform
  }

  const char* Ag = (const char*)(xb + (size_t)m0 * IN_F);
  const char* Bg = (const char*)(wt + (size_t)n0 * IN_F);

  f32x4 acc[8][4];
#pragma unroll
  for (int i = 0; i < 8; ++i)
#pragma unroll
    for (int j2 = 0; j2 < 4; ++j2) acc[i][j2] = (f32x4){0.f, 0.f, 0.f, 0.f};

  short8 aX[4][2], aY[4][2];  // ping-pong A fragment sets
  short8 b[4][2];             // all 4 n-frags (reused in halves)

  // ---- prologue: tile0 (buf0, 4 half-tiles) + tile1 (buf1, 3 half-tiles)
  STAGE(0, 0, 0, 0);
  STAGE(0, 0, 1, 0);
  STAGE(0, 1, 0, 0);
  STAGE(0, 1, 1, 0);
  STAGE(1, 0, 0, 1);
  STAGE(1, 1, 0, 1);
  STAGE(1, 1, 1, 1);
  asm volatile("s_waitcnt vmcnt(6)" ::: "memory");
  __builtin_amdgcn_s_barrier();
  // pre-read ph1 fragments (drained by ph1's PH_PRE lgkmcnt(0))
  READ_A(0, 0, aX);
  READ_B(0, 0);

  // ---- main loop: 2 K-tiles (T in buf0, T+1 in buf1) per iteration.
  // Each phase: MMA of current quad + ds_reads for the NEXT quad in-window.
  for (int it = 0; it < IN_F / 128; ++it) {
    const int T = 2 * it;
    const int P0 = (T + 2) & 63;
    const int P1 = (T + 3) & 63;

    // phase 1: MMA (0,0) of T [aX,b01]; window-read B-h1(T)->b23
    STAGE(1, 0, 1, T + 1);  // A-h1 of T+1 -> buf1
    PH_PRE();
    MMA_Q(aX, 0, 0);
    READ_B(0, 1);
    PH_POST();

    // phase 2: MMA (0,1) [aX,b23]; window-read A-h1(T)->aY
    STAGE(0, 0, 0, P0);  // A-h0 of T+2 (reads of old A-h0 drained ph1 PRE)
    PH_PRE();
    MMA_Q(aX, 0, 1);
    READ_A(0, 1, aY);
    PH_POST();

    // phase 3: MMA (1,0) [aY,b01]; no reads
    STAGE(0, 1, 0, P0);  // B-h0 of T+2
    PH_PRE();
    MMA_Q(aY, 1, 0);
    PH_POST();

    // phase 4: MMA (1,1) [aY,b23]; vmcnt(6) completes buf1 T+1 ->
    // window-read A-h0(T+1)->aX, B-h0(T+1)->b01
    STAGE(0, 1, 1, P0);  // B-h1 of T+2
    asm volatile("s_waitcnt vmcnt(6)" ::: "memory");
    PH_PRE();
    MMA_Q(aY, 1, 1);
    READ_A(1, 0, aX);
    READ_B(1, 0);
    PH_POST();

    // phase 5: MMA (0,0) of T+1 [aX,b01]; window-read B-h1(T+1)->b23
    STAGE(0, 0, 1, P0);  // A-h1 of T+2
    PH_PRE();
    MMA_Q(aX, 0, 0);
    READ_B(1, 1);
    PH_POST();

    // phase 6: MMA (0,1) [aX,b23]; window-read A-h1(T+1)->aY
    STAGE(1, 0, 0, P1);  // A-h0 of T+3 (buf1 A-h0 reads drained ph5 PRE)
    PH_PRE();
    MMA_Q(aX, 0, 1);
    READ_A(1, 1, aY);
    PH_POST();

    // phase 7: MMA (1,0) [aY,b01]; no reads
    STAGE(1, 1, 0, P1);  // B-h0 of T+3
    PH_PRE();
    MMA_Q(aY, 1, 0);
    PH_POST();

    // phase 8: MMA (1,1) [aY,b23]; vmcnt(6) completes buf0 T+2 ->
    // window-read A-h0(T+2)->aX, B-h0(T+2)->b01 (next iter ph1)
    STAGE(1, 1, 1, P1);  // B-h1 of T+3
    asm volatile("s_waitcnt vmcnt(6)" ::: "memory");
    PH_PRE();
    MMA_Q(aY, 1, 1);
    READ_A(0, 0, aX);
    READ_B(0, 0);
    PH_POST();
  }

  // ---- epilogue: C/D layout col=lane&15 (n), row=(lane>>4)*4+reg (m)
  // acc[mf][nf]: m = m0 + (mf>>2)*128 + wr*64 + (mf&3)*16 + h4 + r
  const int h4 = hq * 4;
  float bv[4];
#pragma unroll
  for (int nf = 0; nf < 4; ++nf) bv[nf] = bias[n0 + wc * 64 + nf * 16 + fr];
#pragma unroll
  for (int mf = 0; mf < 8; ++mf) {
    const int m = m0 + (mf >> 2) * 128 + wr * 64 + (mf & 3) * 16 + h4;
#pragma unroll
    for (int nf = 0; nf < 4; ++nf) {
      const int n = n0 + wc * 64 + nf * 16 + fr;
      float* o = out + (size_t)m * OUT_F + n;
#pragma unroll
      for (int r = 0; r < 4; ++r) o[(size_t)r * OUT_F] = acc[mf][nf][r] + bv[nf];
    }
  }
}

// ---------------------------------------------------------------------------
extern "C" void kernel_launch(void* const* d_in, const int* in_sizes, int n_in,
                              void* d_out, int out_size, void* d_ws,
                              size_t ws_size, hipStream_t stream) {
  const float* x = (const float*)d_in[0];
  const int* qweight = (const int*)d_in[1];
  const int* qzeros = (const int*)d_in[2];
  const float* scales = (const float*)d_in[3];
  const float* bias = (const float*)d_in[4];
  float* out = (float*)d_out;

  __hip_bfloat16* xb = (__hip_bfloat16*)d_ws;       // 64 MiB
  __hip_bfloat16* wt = xb + (size_t)TOKENS * IN_F;  // +32 MiB

  // opt-in to 128 KiB dynamic LDS (idempotent; capture-safe)
  (void)hipFuncSetAttribute(reinterpret_cast<const void*>(&k_gemm256),
                            hipFuncAttributeMaxDynamicSharedMemorySize, 131072);

  k_convert_x<<<2048, 256, 0, stream>>>(x, xb);
  k_dequant<<<1024, 256, 0, stream>>>(qweight, qzeros, scales, wt);
  k_gemm256<<<(TOKENS / 256) * (OUT_F / 256), 512, 131072, stream>>>(xb, wt,
                                                                     bias, out);
}